// Round 3
// baseline (3532.884 us; speedup 1.0000x reference)
//
#include <hip/hip_runtime.h>
#include <stdint.h>

typedef unsigned short u16;
typedef unsigned int   u32;
typedef __bf16 bf16v8 __attribute__((ext_vector_type(8)));
typedef float  f32x4  __attribute__((ext_vector_type(4)));

#define DEV static __device__ __forceinline__

DEV int imin(int a, int b){ return a < b ? a : b; }
DEV float bf2f(u16 u){ union{u32 i; float f;} v; v.i = ((u32)u) << 16; return v.f; }
DEV u16 f2bf(float f){ union{float f; u32 i;} v; v.f = f; return (u16)((v.i + 0x7fffu + ((v.i >> 16) & 1u)) >> 16); }
DEV float sigmf(float x){ return 1.0f / (1.0f + __expf(-x)); }
DEV float tanhf_(float x){ return 1.0f - 2.0f / (__expf(2.0f * x) + 1.0f); }

DEV bf16v8 ldb8(const u16* p){ return *reinterpret_cast<const bf16v8*>(p); }
#define MFMA16(a,b,c) __builtin_amdgcn_mfma_f32_16x16x32_bf16(a,b,c,0,0,0)

// ---------------------------------------- convert f32 weights -> padded bf16 ws copies
// row-blocks: [0,2048) WihF | [2048,4096) WihB | [4096,6144) WhhF | [6144,8192) WhhB
// [8192,12288) dWih(1624->1632) | [12288,16384) dWhh | [16384,16688) U1p | [16688,16992) U2p
// [16992,17296) V1p | [17296,17600) V2p | [17600,17856) W1b | [17856,18112) W2b | [18112,18416) Wmp
__global__ __launch_bounds__(256) void cvt_weights(
    const float* eWih_f, const float* eWih_b, const float* eWhh_f, const float* eWhh_b,
    const float* dWih, const float* dWhh,
    const float* U1, const float* U2, const float* V1, const float* V2,
    const float* W1, const float* W2, const float* Wm,
    u16* WihF_p, u16* WihB_p, u16* WhhF, u16* WhhB, u16* dWih_p, u16* dWhh16,
    u16* U1p, u16* U2p, u16* V1p, u16* V2p, u16* W1b, u16* W2b, u16* Wmp)
{
  int blk = blockIdx.x, tid = threadIdx.x;
  const float* src; u16* dst; int sw, dw, valid;
  if (blk < 2048)       { src = eWih_f + (size_t)blk * 300; dst = WihF_p + (size_t)blk * 320; sw = 300; dw = 320; valid = 1; }
  else if (blk < 4096)  { int r = blk - 2048;  src = eWih_b + (size_t)r * 300;  dst = WihB_p + (size_t)r * 320;  sw = 300;  dw = 320;  valid = 1; }
  else if (blk < 6144)  { int r = blk - 4096;  src = eWhh_f + (size_t)r * 512;  dst = WhhF  + (size_t)r * 512;  sw = 512;  dw = 512;  valid = 1; }
  else if (blk < 8192)  { int r = blk - 6144;  src = eWhh_b + (size_t)r * 512;  dst = WhhB  + (size_t)r * 512;  sw = 512;  dw = 512;  valid = 1; }
  else if (blk < 12288) { int r = blk - 8192;  src = dWih  + (size_t)r * 1624; dst = dWih_p + (size_t)r * 1632; sw = 1624; dw = 1632; valid = 1; }
  else if (blk < 16384) { int r = blk - 12288; src = dWhh  + (size_t)r * 1024; dst = dWhh16 + (size_t)r * 1024; sw = 1024; dw = 1024; valid = 1; }
  else if (blk < 16688) { int r = blk - 16384; src = U1 + (size_t)imin(r,299) * 300; dst = U1p + (size_t)r * 320; sw = 300; dw = 320; valid = (r < 300); }
  else if (blk < 16992) { int r = blk - 16688; src = U2 + (size_t)imin(r,299) * 300; dst = U2p + (size_t)r * 320; sw = 300; dw = 320; valid = (r < 300); }
  else if (blk < 17296) { int r = blk - 16992; src = V1 + (size_t)imin(r,299) * 300; dst = V1p + (size_t)r * 320; sw = 300; dw = 320; valid = (r < 300); }
  else if (blk < 17600) { int r = blk - 17296; src = V2 + (size_t)imin(r,299) * 300; dst = V2p + (size_t)r * 320; sw = 300; dw = 320; valid = (r < 300); }
  else if (blk < 17856) { int r = blk - 17600; src = W1 + (size_t)r * 1024; dst = W1b + (size_t)r * 1024; sw = 1024; dw = 1024; valid = 1; }
  else if (blk < 18112) { int r = blk - 17856; src = W2 + (size_t)r * 1024; dst = W2b + (size_t)r * 1024; sw = 1024; dw = 1024; valid = 1; }
  else                  { int r = blk - 18112; src = Wm + (size_t)imin(r,299) * 1024; dst = Wmp + (size_t)r * 1024; sw = 1024; dw = 1024; valid = (r < 300); }
  for (int i = tid; i < dw; i += 256) dst[i] = (valid && i < sw) ? f2bf(src[i]) : (u16)0;
}

// ---------------------------------------------------------------- gather/init (f32 emb -> bf16)
// blocks: [0,160) x_enc | [160,3360) mem rows | [3360,4896) emb_seq | [4896,4928) emb0 | [4928,5056) zero states
__global__ __launch_bounds__(256) void gather_init(
    const int* topics, const int* essay, const int* mems,
    const float* enc_emb, const float* dec_emb, const float* mem_emb,
    u16* x_enc, u16* memb, u16* emb_seq, u16* emb0, u16* h_enc, float* c_enc)
{
  int blk = blockIdx.x, tid = threadIdx.x;
  if (blk < 160) {
    int t = blk / 32, b = blk % 32;
    int tok = topics[b * 5 + t];
    u16* dst = x_enc + (size_t)blk * 320;
    const float* src = enc_emb + (size_t)tok * 300;
    for (int i = tid; i < 320; i += 256) dst[i] = (i < 300) ? f2bf(src[i]) : (u16)0;
  } else if (blk < 3360) {
    int s = blk - 160;
    int tok = mems[s];
    u16* d0 = memb + (size_t)s * 320;
    u16* d1 = memb + (size_t)(3200 + s) * 320;
    const float* src = mem_emb + (size_t)tok * 300;
    for (int i = tid; i < 320; i += 256) { d0[i] = (i < 300) ? f2bf(src[i]) : (u16)0; d1[i] = 0; }
  } else if (blk < 4896) {
    int r = blk - 3360;
    int t = r / 32, b = r % 32;
    int tok = essay[b * 48 + (t < 47 ? t + 1 : 47)];
    u16* dst = emb_seq + (size_t)r * 320;
    const float* src = dec_emb + (size_t)tok * 300;
    for (int i = tid; i < 320; i += 256) dst[i] = (i < 300) ? f2bf(src[i]) : (u16)0;
  } else if (blk < 4928) {
    int b = blk - 4896;
    int tok = essay[b * 48];
    u16* dst = emb0 + (size_t)b * 320;
    const float* src = dec_emb + (size_t)tok * 300;
    for (int i = tid; i < 320; i += 256) dst[i] = (i < 300) ? f2bf(src[i]) : (u16)0;
  } else {
    int id = blk - 4928;
    if (id < 64) {
      int dir = id / 32, m = id % 32;
      u16* p = h_enc + ((size_t)(dir * 2 + 0) * 32 + m) * 512;
      for (int i = tid; i < 512; i += 256) p[i] = 0;
    } else {
      int id2 = id - 64;
      int dir = id2 / 32, m = id2 % 32;
      float* p = c_enc + ((size_t)(dir * 2 + 0) * 32 + m) * 512;
      for (int i = tid; i < 512; i += 256) p[i] = 0.0f;
    }
  }
}

// ------------------------------------------------- vemb = [emb@V1.T+bV1 | emb@V2.T+bV2]
__global__ __launch_bounds__(256) void vemb_gemm(
    const u16* emb_seq, const u16* V1p, const u16* V2p, const float* bV1, const float* bV2, float* vemb)
{
  int m0 = blockIdx.x * 32;
  int tid = threadIdx.x, w = tid >> 6, lane = tid & 63;
  int lr = lane & 15, lk = (lane >> 4) * 8;
  const u16* ur[10]; int cols[10];
  f32x4 acc0[10], acc1[10];
  #pragma unroll
  for (int i = 0; i < 10; ++i) {
    acc0[i] = (f32x4){0,0,0,0}; acc1[i] = (f32x4){0,0,0,0};
    int col = (w * 10 + i) * 16 + lr; cols[i] = col;
    if (col < 304)      ur[i] = V1p + (size_t)col * 320;
    else if (col < 608) ur[i] = V2p + (size_t)(col - 304) * 320;
    else                ur[i] = V1p;
  }
  for (int k0 = 0; k0 < 320; k0 += 32) {
    bf16v8 a0 = ldb8(emb_seq + (size_t)(m0 + lr) * 320 + k0 + lk);
    bf16v8 a1 = ldb8(emb_seq + (size_t)(m0 + 16 + lr) * 320 + k0 + lk);
    #pragma unroll
    for (int i = 0; i < 10; ++i) {
      bf16v8 b = ldb8(ur[i] + k0 + lk);
      acc0[i] = MFMA16(a0, b, acc0[i]);
      acc1[i] = MFMA16(a1, b, acc1[i]);
    }
  }
  int rb = (lane >> 4) * 4;
  #pragma unroll
  for (int i = 0; i < 10; ++i) {
    int col = cols[i];
    if (col >= 608) continue;
    float bb = (col < 304) ? ((col < 300) ? bV1[col] : 0.f) : ((col - 304 < 300) ? bV2[col - 304] : 0.f);
    #pragma unroll
    for (int r = 0; r < 4; ++r) {
      vemb[(size_t)(m0 + rb + r) * 608 + col]      = acc0[i][r] + bb;
      vemb[(size_t)(m0 + 16 + rb + r) * 608 + col] = acc1[i][r] + bb;
    }
  }
}

// ---------------------------------------------------------------- encoder step
__global__ __launch_bounds__(256) void enc_step(
    int t, const u16* x_enc,
    const u16* WihF_p, const u16* WhhF, const float* b_f,
    const u16* WihB_p, const u16* WhhB, const float* b_b,
    u16* h_enc, float* c_enc, float* ys_f, float* ys_b)
{
  int blk = blockIdx.x, tid = threadIdx.x;
  int dir = blk >> 5, jb = blk & 31, j0 = jb * 16;
  int w = tid >> 6, lane = tid & 63, lr = lane & 15, lk = (lane >> 4) * 8;
  const u16* Wih = dir ? WihB_p : WihF_p;
  const u16* Whh = dir ? WhhB : WhhF;
  const float* bias = dir ? b_b : b_f;
  const u16* xrow = x_enc + (size_t)(dir ? (4 - t) : t) * 32 * 320;
  const u16* h_prev = h_enc + ((size_t)(dir * 2 + (t & 1)) * 32) * 512;
  u16* h_next = h_enc + ((size_t)(dir * 2 + ((t + 1) & 1)) * 32) * 512;
  const float* c_prev = c_enc + ((size_t)(dir * 2 + (t & 1)) * 32) * 512;
  float* c_next = c_enc + ((size_t)(dir * 2 + ((t + 1) & 1)) * 32) * 512;
  float* ys = (dir ? ys_b : ys_f) + (size_t)t * 32 * 512;

  int wrow = w * 512 + j0 + lr;
  f32x4 acc0 = {0,0,0,0}, acc1 = {0,0,0,0};
  const u16* bp1 = Wih + (size_t)wrow * 320;
  #pragma unroll 2
  for (int k0 = 0; k0 < 320; k0 += 32) {
    bf16v8 b = ldb8(bp1 + k0 + lk);
    bf16v8 a0 = ldb8(xrow + (size_t)lr * 320 + k0 + lk);
    bf16v8 a1 = ldb8(xrow + (size_t)(lr + 16) * 320 + k0 + lk);
    acc0 = MFMA16(a0, b, acc0); acc1 = MFMA16(a1, b, acc1);
  }
  const u16* bp2 = Whh + (size_t)wrow * 512;
  #pragma unroll 4
  for (int k0 = 0; k0 < 512; k0 += 32) {
    bf16v8 b = ldb8(bp2 + k0 + lk);
    bf16v8 a0 = ldb8(h_prev + (size_t)lr * 512 + k0 + lk);
    bf16v8 a1 = ldb8(h_prev + (size_t)(lr + 16) * 512 + k0 + lk);
    acc0 = MFMA16(a0, b, acc0); acc1 = MFMA16(a1, b, acc1);
  }
  float bb = bias[wrow];
  __shared__ float lg[4][32][16];
  int rb = (lane >> 4) * 4;
  #pragma unroll
  for (int r = 0; r < 4; ++r) {
    lg[w][rb + r][lr] = acc0[r] + bb;
    lg[w][16 + rb + r][lr] = acc1[r] + bb;
  }
  __syncthreads();
  for (int i = tid; i < 512; i += 256) {
    int m = i >> 4, jj = i & 15, col = j0 + jj;
    float ig = lg[0][m][jj], fg = lg[1][m][jj], gg = lg[2][m][jj], og = lg[3][m][jj];
    float c_old = c_prev[(size_t)m * 512 + col];
    float c2 = sigmf(fg) * c_old + sigmf(ig) * tanhf_(gg);
    float h2 = sigmf(og) * tanhf_(c2);
    c_next[(size_t)m * 512 + col] = c2;
    h_next[(size_t)m * 512 + col] = f2bf(h2);
    ys[(size_t)m * 512 + col] = h2;
  }
}

// ------------------------------------- prep: h0/c0 (weird reshape), TR_CT, tr_pre
__global__ __launch_bounds__(256) void prep_kernel(
    const float* ys_f, const float* ys_b, const float* c_enc,
    u16* h_pp, float* c_pp, u16* c_bfpp, float* TR_CT, u16* tr_pre)
{
  int blk = blockIdx.x, tid = threadIdx.x;
  if (blk < 32) {
    int r = blk;
    for (int c = tid; c < 1024; c += 256) {
      int bs = 2 * (r & 15) + (c >> 9), k = c & 511;
      const float* ysX = (r < 16) ? ys_f : ys_b;
      float hv = ysX[((size_t)4 * 32 + bs) * 512 + k];
      float cv = c_enc[((size_t)(((r < 16) ? 0 : 1) * 2 + 1) * 32 + bs) * 512 + k];
      h_pp[(size_t)r * 1024 + c] = f2bf(hv);
      c_pp[(size_t)r * 1024 + c] = cv;
      c_bfpp[(size_t)r * 1024 + c] = f2bf(cv);
    }
  } else if (blk < 64) {
    int b2 = blk - 32;
    for (int i = tid; i < 5120; i += 256) {
      int f = b2 * 5120 + i;
      int tt = f >> 15, bb = (f >> 10) & 31, dd = f & 1023;
      float v = (dd < 512) ? ys_f[((size_t)tt * 32 + bb) * 512 + dd]
                           : ys_b[((size_t)(4 - tt) * 32 + bb) * 512 + (dd - 512)];
      TR_CT[(size_t)b2 * 5120 + i] = v;
    }
  } else {
    int i = blk - 64;
    int st = i >> 5, sb = i & 31;
    for (int c = tid; c < 1024; c += 256) {
      float v = (c < 512) ? ys_f[((size_t)st * 32 + sb) * 512 + c]
                          : ys_b[((size_t)(4 - st) * 32 + sb) * 512 + (c - 512)];
      tr_pre[(size_t)i * 1024 + c] = f2bf(v);
    }
  }
}

// ----------------------------------------- pre = tr_pre @ W1.T + b1  (160x256, K=1024)
__global__ __launch_bounds__(64) void pre_gemm(const u16* tr_pre, const u16* W1b, const float* b1, float* pre)
{
  int blk = blockIdx.x, mt = blk >> 4, nt = blk & 15;
  int lane = threadIdx.x & 63, lr = lane & 15, lk = (lane >> 4) * 8;
  int col = nt * 16 + lr;
  f32x4 acc = {0,0,0,0};
  const u16* brow = W1b + (size_t)col * 1024;
  const u16* arow = tr_pre + (size_t)(mt * 16 + lr) * 1024;
  #pragma unroll 4
  for (int k0 = 0; k0 < 1024; k0 += 32)
    acc = MFMA16(ldb8(arow + k0 + lk), ldb8(brow + k0 + lk), acc);
  float bb = b1[col];
  int rb = (lane >> 4) * 4;
  #pragma unroll
  for (int r = 0; r < 4; ++r)
    pre[(size_t)(mt * 16 + rb + r) * 256 + col] = acc[r] + bb;
}

// ------------------------------------------------ decoder step A: LSTM + mem update
__global__ __launch_bounds__(256) void dec_stepA(
    int t, const u16* dec_in, const u16* dWih_p, const u16* dWhh16, const float* dbias,
    u16* h_pp, float* c_pp, u16* c_bfpp, u16* h_seq,
    u16* memb, const u16* U1p, const u16* U2p, const float* bU1, const float* bU2, const float* vemb)
{
  int blk = blockIdx.x, tid = threadIdx.x;
  int w = tid >> 6, lane = tid & 63, lr = lane & 15, lk = (lane >> 4) * 8;
  __shared__ float lg[4][32][16];
  if (blk < 64) {
    int j0 = blk * 16;
    const u16* h_prev = h_pp + (size_t)(t & 1) * 32768;
    u16* h_next = h_pp + (size_t)((t + 1) & 1) * 32768;
    const float* c_prev = c_pp + (size_t)(t & 1) * 32768;
    float* c_next = c_pp + (size_t)((t + 1) & 1) * 32768;
    u16* cb_next = c_bfpp + (size_t)((t + 1) & 1) * 32768;
    int wrow = w * 1024 + j0 + lr;
    f32x4 acc0 = {0,0,0,0}, acc1 = {0,0,0,0};
    const u16* bp1 = dWih_p + (size_t)wrow * 1632;
    #pragma unroll 4
    for (int k0 = 0; k0 < 1632; k0 += 32) {
      bf16v8 b = ldb8(bp1 + k0 + lk);
      bf16v8 a0 = ldb8(dec_in + (size_t)lr * 1632 + k0 + lk);
      bf16v8 a1 = ldb8(dec_in + (size_t)(lr + 16) * 1632 + k0 + lk);
      acc0 = MFMA16(a0, b, acc0); acc1 = MFMA16(a1, b, acc1);
    }
    const u16* bp2 = dWhh16 + (size_t)wrow * 1024;
    #pragma unroll 4
    for (int k0 = 0; k0 < 1024; k0 += 32) {
      bf16v8 b = ldb8(bp2 + k0 + lk);
      bf16v8 a0 = ldb8(h_prev + (size_t)lr * 1024 + k0 + lk);
      bf16v8 a1 = ldb8(h_prev + (size_t)(lr + 16) * 1024 + k0 + lk);
      acc0 = MFMA16(a0, b, acc0); acc1 = MFMA16(a1, b, acc1);
    }
    float bb = dbias[wrow];
    int rb = (lane >> 4) * 4;
    #pragma unroll
    for (int r = 0; r < 4; ++r) {
      lg[w][rb + r][lr] = acc0[r] + bb;
      lg[w][16 + rb + r][lr] = acc1[r] + bb;
    }
    __syncthreads();
    for (int i = tid; i < 512; i += 256) {
      int m = i >> 4, jj = i & 15, col = j0 + jj;
      float ig = lg[0][m][jj], fg = lg[1][m][jj], gg = lg[2][m][jj], og = lg[3][m][jj];
      float c_old = c_prev[(size_t)m * 1024 + col];
      float c2 = sigmf(fg) * c_old + sigmf(ig) * tanhf_(gg);
      float h2 = sigmf(og) * tanhf_(c2);
      c_next[(size_t)m * 1024 + col] = c2;
      cb_next[(size_t)m * 1024 + col] = f2bf(c2);
      h_next[(size_t)m * 1024 + col] = f2bf(h2);
      h_seq[((size_t)t * 32 + m) * 1024 + col] = f2bf(h2);
    }
  } else {
    if (t == 47) return;
    int s0 = (blk - 64) * 32;
    const u16* mcur = memb + (size_t)(t & 1) * 3200 * 320;
    u16* mnext = memb + (size_t)((t + 1) & 1) * 3200 * 320;
    int jt0 = w * 5, njt = (w == 3) ? 4 : 5;
    f32x4 accA[2][5], accB[2][5];
    const u16 *r1[5], *r2[5];
    #pragma unroll
    for (int i = 0; i < 5; ++i) {
      accA[0][i] = (f32x4){0,0,0,0}; accA[1][i] = (f32x4){0,0,0,0};
      accB[0][i] = (f32x4){0,0,0,0}; accB[1][i] = (f32x4){0,0,0,0};
      int col = (jt0 + i) * 16 + lr; int cc = imin(col, 303);
      r1[i] = U1p + (size_t)cc * 320; r2[i] = U2p + (size_t)cc * 320;
    }
    for (int k0 = 0; k0 < 320; k0 += 32) {
      bf16v8 a0 = ldb8(mcur + (size_t)(s0 + lr) * 320 + k0 + lk);
      bf16v8 a1 = ldb8(mcur + (size_t)(s0 + 16 + lr) * 320 + k0 + lk);
      #pragma unroll
      for (int i = 0; i < 5; ++i) {
        if (i < njt) {
          bf16v8 b1v = ldb8(r1[i] + k0 + lk);
          bf16v8 b2v = ldb8(r2[i] + k0 + lk);
          accA[0][i] = MFMA16(a0, b1v, accA[0][i]);
          accA[1][i] = MFMA16(a1, b1v, accA[1][i]);
          accB[0][i] = MFMA16(a0, b2v, accB[0][i]);
          accB[1][i] = MFMA16(a1, b2v, accB[1][i]);
        }
      }
    }
    int rb = (lane >> 4) * 4;
    #pragma unroll
    for (int i = 0; i < 5; ++i) {
      if (i >= njt) break;
      int col = (jt0 + i) * 16 + lr;
      if (col >= 300) continue;
      float bu1 = bU1[col], bu2 = bU2[col];
      #pragma unroll
      for (int mt = 0; mt < 2; ++mt) {
        #pragma unroll
        for (int r = 0; r < 4; ++r) {
          int slot = s0 + mt * 16 + rb + r;
          int bb = slot / 100;
          const float* vrow = vemb + ((size_t)t * 32 + bb) * 608;
          float mtp = (mt ? accA[1][i][r] : accA[0][i][r]) + bu1 + vrow[col];
          float gp  = (mt ? accB[1][i][r] : accB[0][i][r]) + bu2 + vrow[304 + col];
          float old = bf2f(mcur[(size_t)slot * 320 + col]);
          float g = sigmf(gp);
          mnext[(size_t)slot * 320 + col] = f2bf(tanhf_(mtp) * g + old * (1.0f - g));
        }
      }
    }
  }
}

// --------------------------------------- B1: q = c@W2.T+b2 ; v = tanh(h@Wm.T+bm)
__global__ __launch_bounds__(64) void dec_stepB1(
    int t, const u16* h_pp, const u16* c_bfpp,
    const u16* W2b, const float* b2, const u16* Wmp, const float* bm,
    float* q_all, float* v_all)
{
  int blk = blockIdx.x, lane = threadIdx.x & 63;
  int lr = lane & 15, lk = (lane >> 4) * 8;
  int pp = (t + 1) & 1;
  const u16* h = h_pp + (size_t)pp * 32768;
  const u16* c = c_bfpp + (size_t)pp * 32768;
  f32x4 acc0 = {0,0,0,0}, acc1 = {0,0,0,0};
  int rb = (lane >> 4) * 4;
  if (blk < 16) {
    int col = blk * 16 + lr;
    const u16* brow = W2b + (size_t)col * 1024;
    #pragma unroll 4
    for (int k0 = 0; k0 < 1024; k0 += 32) {
      bf16v8 b = ldb8(brow + k0 + lk);
      acc0 = MFMA16(ldb8(c + (size_t)lr * 1024 + k0 + lk), b, acc0);
      acc1 = MFMA16(ldb8(c + (size_t)(lr + 16) * 1024 + k0 + lk), b, acc1);
    }
    float bb = b2[col];
    #pragma unroll
    for (int r = 0; r < 4; ++r) {
      q_all[(size_t)(rb + r) * 256 + col] = acc0[r] + bb;
      q_all[(size_t)(16 + rb + r) * 256 + col] = acc1[r] + bb;
    }
  } else {
    int col = (blk - 16) * 16 + lr;
    const u16* brow = Wmp + (size_t)imin(col, 303) * 1024;
    #pragma unroll 4
    for (int k0 = 0; k0 < 1024; k0 += 32) {
      bf16v8 b = ldb8(brow + k0 + lk);
      acc0 = MFMA16(ldb8(h + (size_t)lr * 1024 + k0 + lk), b, acc0);
      acc1 = MFMA16(ldb8(h + (size_t)(lr + 16) * 1024 + k0 + lk), b, acc1);
    }
    if (col < 300) {
      float bb = bm[col];
      #pragma unroll
      for (int r = 0; r < 4; ++r) {
        v_all[(size_t)(rb + r) * 304 + col] = tanhf_(acc0[r] + bb);
        v_all[(size_t)(16 + rb + r) * 304 + col] = tanhf_(acc1[r] + bb);
      }
    }
  }
}

// --------------------------------------- B2: attention + memory read + concat dec_in
__global__ __launch_bounds__(256) void dec_stepB2(
    int t, const float* q_all, const float* v_all, const float* pre,
    const float* W3, const float* b3, const float* TR_CT,
    const u16* memb, const u16* emb_seq, const u16* emb0, u16* dec_in)
{
  int b = blockIdx.x, tid = threadIdx.x;
  __shared__ float sq[256], red[256], se[5], salpha[5], sv[304], ssc[100], sqm[100], ssum[2];
  const u16* mrow = memb + (size_t)((t + 1) & 1) * 3200 * 320 + (size_t)b * 100 * 320;
  const u16* erow = (t < 0) ? (emb0 + (size_t)b * 320) : (emb_seq + ((size_t)t * 32 + b) * 320);
  u16* drow = dec_in + (size_t)b * 1632;

  sq[tid] = q_all[(size_t)b * 256 + tid];
  __syncthreads();
  for (int tn = 0; tn < 5; ++tn) {
    red[tid] = pre[((size_t)b * 5 + tn) * 256 + tid] * sq[tid];
    __syncthreads();
    for (int s = 128; s > 0; s >>= 1) { if (tid < s) red[tid] += red[tid + s]; __syncthreads(); }
    if (tid == 0) se[tn] = tanhf_(red[0]);
    __syncthreads();
  }
  if (tid == 0) {
    float e2[5]; float mx = -1e30f;
    for (int j = 0; j < 5; ++j) {
      float s = b3[j];
      for (int tn = 0; tn < 5; ++tn) s += se[tn] * W3[j * 5 + tn];
      e2[j] = s; mx = fmaxf(mx, s);
    }
    float sum = 0.f;
    for (int j = 0; j < 5; ++j) { e2[j] = __expf(e2[j] - mx); sum += e2[j]; }
    float inv = 1.f / sum;
    for (int j = 0; j < 5; ++j) salpha[j] = e2[j] * inv;
  }
  __syncthreads();
  for (int d = tid; d < 1024; d += 256) {
    const float* tc = TR_CT + ((size_t)b * 1024 + d) * 5;
    float ct = tc[0]*salpha[0] + tc[1]*salpha[1] + tc[2]*salpha[2] + tc[3]*salpha[3] + tc[4]*salpha[4];
    drow[300 + d] = f2bf(ct);
  }
  for (int i = tid; i < 304; i += 256) sv[i] = (i < 300) ? v_all[(size_t)b * 304 + i] : 0.f;
  __syncthreads();
  if (tid < 100) {
    const u16* mr = mrow + (size_t)tid * 320;
    float s = 0.f;
    for (int e = 0; e < 300; ++e) s += bf2f(mr[e]) * sv[e];
    ssc[tid] = s;
  }
  __syncthreads();
  if (tid == 0) { float mx = -1e30f; for (int l = 0; l < 100; ++l) mx = fmaxf(mx, ssc[l]); ssum[0] = mx; }
  __syncthreads();
  if (tid < 100) sqm[tid] = __expf(ssc[tid] - ssum[0]);
  __syncthreads();
  if (tid == 0) { float s = 0.f; for (int l = 0; l < 100; ++l) s += sqm[l]; ssum[1] = 1.f / s; }
  __syncthreads();
  float inv = ssum[1];
  for (int e = tid; e < 300; e += 256) {
    float acc = 0.f;
    for (int l = 0; l < 100; ++l) acc += sqm[l] * bf2f(mrow[(size_t)l * 320 + e]);
    drow[1324 + e] = f2bf(acc * inv);
    drow[e] = erow[e];
  }
  if (tid < 8) drow[1624 + tid] = 0;
}

// ---------------------------------------------- logits = h_seq @ Wfc.T + bfc  (f32 in/out)
__global__ __launch_bounds__(256) void logits_gemm(
    const u16* h_seq, const float* Wfc, const float* bfc, float* out)
{
  __shared__ u16 As[128 * 40], Bs[128 * 40];
  int tid = threadIdx.x;
  int n0 = blockIdx.x * 128, m0 = blockIdx.y * 128;
  int w = tid >> 6, lane = tid & 63, lr = lane & 15, lk = (lane >> 4) * 8;
  int wr = w >> 1, wc = w & 1;
  int sr = tid >> 1, sc = (tid & 1) * 16;
  const u16* ga = h_seq + (size_t)(m0 + sr) * 1024 + sc;
  int brow = n0 + sr; if (brow > 49999) brow = 49999;
  const float* gb = Wfc + (size_t)brow * 1024 + sc;
  f32x4 acc[4][4];
  #pragma unroll
  for (int i = 0; i < 4; ++i)
    #pragma unroll
    for (int j = 0; j < 4; ++j) acc[i][j] = (f32x4){0,0,0,0};

  bf16v8 pa0 = ldb8(ga), pa1 = ldb8(ga + 8);
  float4 qb0 = *(const float4*)(gb), qb1 = *(const float4*)(gb + 4);
  float4 qb2 = *(const float4*)(gb + 8), qb3 = *(const float4*)(gb + 12);
  for (int kt = 0; kt < 32; ++kt) {
    __syncthreads();
    *reinterpret_cast<bf16v8*>(&As[sr * 40 + sc]) = pa0;
    *reinterpret_cast<bf16v8*>(&As[sr * 40 + sc + 8]) = pa1;
    u16* bd = &Bs[sr * 40 + sc];
    bd[0] = f2bf(qb0.x); bd[1] = f2bf(qb0.y); bd[2] = f2bf(qb0.z); bd[3] = f2bf(qb0.w);
    bd[4] = f2bf(qb1.x); bd[5] = f2bf(qb1.y); bd[6] = f2bf(qb1.z); bd[7] = f2bf(qb1.w);
    bd[8] = f2bf(qb2.x); bd[9] = f2bf(qb2.y); bd[10] = f2bf(qb2.z); bd[11] = f2bf(qb2.w);
    bd[12] = f2bf(qb3.x); bd[13] = f2bf(qb3.y); bd[14] = f2bf(qb3.z); bd[15] = f2bf(qb3.w);
    __syncthreads();
    if (kt < 31) {
      int k = (kt + 1) * 32;
      pa0 = ldb8(ga + k); pa1 = ldb8(ga + k + 8);
      qb0 = *(const float4*)(gb + k); qb1 = *(const float4*)(gb + k + 4);
      qb2 = *(const float4*)(gb + k + 8); qb3 = *(const float4*)(gb + k + 12);
    }
    bf16v8 af[4], bf[4];
    #pragma unroll
    for (int mi = 0; mi < 4; ++mi)
      af[mi] = *reinterpret_cast<const bf16v8*>(&As[(wr * 64 + mi * 16 + lr) * 40 + lk]);
    #pragma unroll
    for (int ni = 0; ni < 4; ++ni)
      bf[ni] = *reinterpret_cast<const bf16v8*>(&Bs[(wc * 64 + ni * 16 + lr) * 40 + lk]);
    #pragma unroll
    for (int mi = 0; mi < 4; ++mi)
      #pragma unroll
      for (int ni = 0; ni < 4; ++ni)
        acc[mi][ni] = MFMA16(af[mi], bf[ni], acc[mi][ni]);
  }
  int rb = (lane >> 4) * 4;
  #pragma unroll
  for (int mi = 0; mi < 4; ++mi) {
    #pragma unroll
    for (int ni = 0; ni < 4; ++ni) {
      int col = n0 + wc * 64 + ni * 16 + lr;
      if (col < 50000) {
        float bb = bfc[col];
        int row = m0 + wr * 64 + mi * 16 + rb;
        #pragma unroll
        for (int r = 0; r < 4; ++r)
          out[(size_t)(row + r) * 50000 + col] = acc[mi][ni][r] + bb;
      }
    }
  }
}

// ================================================================ host launcher
extern "C" void kernel_launch(void* const* d_in, const int* in_sizes, int n_in,
                              void* d_out, int out_size, void* d_ws, size_t ws_size,
                              hipStream_t stream)
{
  (void)in_sizes; (void)n_in; (void)out_size; (void)ws_size;
  const int* topics = (const int*)d_in[0];
  const int* essay  = (const int*)d_in[1];
  const int* mems   = (const int*)d_in[2];
  const float* enc_emb = (const float*)d_in[3];
  const float* eWih_f = (const float*)d_in[4];
  const float* eWhh_f = (const float*)d_in[5];
  const float* eb_f   = (const float*)d_in[6];
  const float* eWih_b = (const float*)d_in[7];
  const float* eWhh_b = (const float*)d_in[8];
  const float* eb_b   = (const float*)d_in[9];
  const float* dec_emb = (const float*)d_in[10];
  const float* dWih   = (const float*)d_in[11];
  const float* dWhh   = (const float*)d_in[12];
  const float* db_    = (const float*)d_in[13];
  const float* Wfc    = (const float*)d_in[14];
  const float* bfc    = (const float*)d_in[15];
  const float* mem_emb = (const float*)d_in[16];
  const float* Wm     = (const float*)d_in[17];
  const float* bm     = (const float*)d_in[18];
  const float* U1     = (const float*)d_in[19];
  const float* bU1    = (const float*)d_in[20];
  const float* V1     = (const float*)d_in[21];
  const float* bV1    = (const float*)d_in[22];
  const float* U2     = (const float*)d_in[23];
  const float* bU2    = (const float*)d_in[24];
  const float* V2     = (const float*)d_in[25];
  const float* bV2    = (const float*)d_in[26];
  const float* W1     = (const float*)d_in[27];
  const float* b1     = (const float*)d_in[28];
  const float* W2     = (const float*)d_in[29];
  const float* b2     = (const float*)d_in[30];
  const float* W3     = (const float*)d_in[31];
  const float* b3     = (const float*)d_in[32];

  char* ws = (char*)d_ws;
  size_t off = 0;
  auto alloc = [&](size_t bytes) -> char* {
    char* p = ws + off; off += (bytes + 255) & ~(size_t)255; return p;
  };
  float* ys_f  = (float*)alloc((size_t)5*32*512*4);
  float* ys_b  = (float*)alloc((size_t)5*32*512*4);
  float* c_enc = (float*)alloc((size_t)2*2*32*512*4);
  float* c_pp  = (float*)alloc((size_t)2*32*1024*4);
  float* TR_CT = (float*)alloc((size_t)32*1024*5*4);
  float* pre   = (float*)alloc((size_t)160*256*4);
  float* vemb  = (float*)alloc((size_t)1536*608*4);
  float* q_all = (float*)alloc((size_t)32*256*4);
  float* v_all = (float*)alloc((size_t)32*304*4);
  u16* x_enc   = (u16*)alloc((size_t)160*320*2);
  u16* emb_seq = (u16*)alloc((size_t)1536*320*2);
  u16* emb0    = (u16*)alloc((size_t)32*320*2);
  u16* memb    = (u16*)alloc((size_t)2*3200*320*2);
  u16* h_enc   = (u16*)alloc((size_t)2*2*32*512*2);
  u16* h_pp    = (u16*)alloc((size_t)2*32*1024*2);
  u16* c_bfpp  = (u16*)alloc((size_t)2*32*1024*2);
  u16* dec_in  = (u16*)alloc((size_t)32*1632*2);
  u16* tr_pre  = (u16*)alloc((size_t)160*1024*2);
  u16* h_seq   = (u16*)alloc((size_t)1536*1024*2);
  u16* WihF_p  = (u16*)alloc((size_t)2048*320*2);
  u16* WihB_p  = (u16*)alloc((size_t)2048*320*2);
  u16* WhhF    = (u16*)alloc((size_t)2048*512*2);
  u16* WhhB    = (u16*)alloc((size_t)2048*512*2);
  u16* dWih_p  = (u16*)alloc((size_t)4096*1632*2);
  u16* dWhh16  = (u16*)alloc((size_t)4096*1024*2);
  u16* U1p     = (u16*)alloc((size_t)304*320*2);
  u16* U2p     = (u16*)alloc((size_t)304*320*2);
  u16* V1p     = (u16*)alloc((size_t)304*320*2);
  u16* V2p     = (u16*)alloc((size_t)304*320*2);
  u16* W1b     = (u16*)alloc((size_t)256*1024*2);
  u16* W2b     = (u16*)alloc((size_t)256*1024*2);
  u16* Wmp     = (u16*)alloc((size_t)304*1024*2);
  float* out   = (float*)d_out;

  cvt_weights<<<18416, 256, 0, stream>>>(eWih_f, eWih_b, eWhh_f, eWhh_b, dWih, dWhh,
                                         U1, U2, V1, V2, W1, W2, Wm,
                                         WihF_p, WihB_p, WhhF, WhhB, dWih_p, dWhh16,
                                         U1p, U2p, V1p, V2p, W1b, W2b, Wmp);
  gather_init<<<5056, 256, 0, stream>>>(topics, essay, mems, enc_emb, dec_emb, mem_emb,
                                        x_enc, memb, emb_seq, emb0, h_enc, c_enc);
  vemb_gemm<<<48, 256, 0, stream>>>(emb_seq, V1p, V2p, bV1, bV2, vemb);
  for (int t = 0; t < 5; ++t)
    enc_step<<<64, 256, 0, stream>>>(t, x_enc, WihF_p, WhhF, eb_f, WihB_p, WhhB, eb_b,
                                     h_enc, c_enc, ys_f, ys_b);
  prep_kernel<<<224, 256, 0, stream>>>(ys_f, ys_b, c_enc, h_pp, c_pp, c_bfpp, TR_CT, tr_pre);
  pre_gemm<<<160, 64, 0, stream>>>(tr_pre, W1b, b1, pre);
  dec_stepB1<<<35, 64, 0, stream>>>(-1, h_pp, c_bfpp, W2b, b2, Wmp, bm, q_all, v_all);
  dec_stepB2<<<32, 256, 0, stream>>>(-1, q_all, v_all, pre, W3, b3, TR_CT, memb, emb_seq, emb0, dec_in);
  for (int t = 0; t < 48; ++t) {
    dec_stepA<<<164, 256, 0, stream>>>(t, dec_in, dWih_p, dWhh16, db_, h_pp, c_pp, c_bfpp, h_seq,
                                       memb, U1p, U2p, bU1, bU2, vemb);
    if (t < 47) {
      dec_stepB1<<<35, 64, 0, stream>>>(t, h_pp, c_bfpp, W2b, b2, Wmp, bm, q_all, v_all);
      dec_stepB2<<<32, 256, 0, stream>>>(t, q_all, v_all, pre, W3, b3, TR_CT, memb, emb_seq, emb0, dec_in);
    }
  }
  logits_gemm<<<dim3(391, 12), 256, 0, stream>>>(h_seq, Wfc, bfc, out);
}